// Round 11
// baseline (198.504 us; speedup 1.0000x reference)
//
#include <hip/hip_runtime.h>
#include <stdint.h>

// SupConLossWithPrototype on MI355X.
// Round 22: R10's cooperative fusion silently no-op'd (absmax == |loss| ->
// out stayed at memset-0; hipLaunchCooperativeKernel under graph capture).
// Same fusion goal, capture-safe mechanism: ticket-counter tail blocks.
//  - phase 1: byte-identical to the passing R9 k_sym (528 x 512).
//  - each block: __threadfence(); ticket = atomicAdd(&g_counter, 1).
//    g_counter is a module-scope __device__ int (.bss -> NOT poisoned by the
//    harness workspace fill). Monotonic epochs: base = (ticket/NBLK)*NBLK,
//    rank = ticket-base -> no reset needed across iterations/graph replays.
//  - last 64 finishers (rank >= NBLK-64) spin until counter reaches
//    base+NBLK (atomicAdd(,0) device-scope read + s_sleep), __threadfence()
//    acquire, then run one 128-row slice of the loss assembly (R10 phase 2).
//  - deadlock-free at any occupancy: non-tail blocks never wait.
// Saves the k_final dispatch + one inter-kernel gap (~13-16us predicted).

#define M_TOT 8192
#define K_DIM 128
#define B_PRO 100
#define INV_T 5.0f                          // 1/TEMP
#define C_SCALE 7.2134752044448170f         // 5 * log2(e)
#define LN2    0.6931471805599453f
#define RT    256                           // tile side
#define NT    (M_TOT / RT)                  // 32 row/col groups
#define NPAIR (NT * (NT - 1) / 2)           // 496 strict upper pairs
#define NBLK  (NT + NPAIR)                  // 528 blocks
#define NTAIL 64                            // tail blocks running phase 2
#define BS    136                           // B/proto LDS stride (bf16 elems)
#define PB    112                           // padded proto rows (7 groups of 16)

#if __has_builtin(__builtin_amdgcn_exp2f)
#define EXP2(x) __builtin_amdgcn_exp2f(x)
#else
#define EXP2(x) __expf((x) * 0.6931471805599453f)
#endif

typedef __attribute__((ext_vector_type(8))) short  short8;   // 8 bf16 (MFMA A/B frag)
typedef __attribute__((ext_vector_type(4))) float  floatx4;  // MFMA C/D frag

__device__ int g_counter;                   // .bss, zero at module load

__device__ __forceinline__ float bf2f(unsigned short u) {
    union { unsigned int i; float f; } v; v.i = ((unsigned int)u) << 16; return v.f;
}
// HW RNE convert: compiler emits v_cvt_pk_bf16_f32 for paired uses.
__device__ __forceinline__ unsigned short f2bf(float x) {
    __bf16 b = (__bf16)x;
    return __builtin_bit_cast(unsigned short, b);
}
__device__ __forceinline__ short8 pack8(float4 a, float4 b) {
    short8 r;
    r[0] = (short)f2bf(a.x); r[1] = (short)f2bf(a.y);
    r[2] = (short)f2bf(a.z); r[3] = (short)f2bf(a.w);
    r[4] = (short)f2bf(b.x); r[5] = (short)f2bf(b.y);
    r[6] = (short)f2bf(b.z); r[7] = (short)f2bf(b.w);
    return r;
}

// ---------------------------------------------------------------- tile body
// One 256x256 tile, 512 threads (8 waves x 32 rows). Operands converted
// in-block from f32 feat; B staged to LDS bf16(C*f) in two 128-col phases.
// accE = sum exp2(D)*mask, row and col direction (raw-logit sums via the
// g-trick in phase 2). DIAG excludes row==col exactly, accumulates the
// novel-masked colsum of its staged tile into gpart, and afterwards computes
// the proto GEMM for its 256 rows (reusing afr + ldsB).
template<bool DIAG>
__device__ __forceinline__ void sym_body(
        int a, int b, int R0, int C0,
        const float* __restrict__ feat, const int* __restrict__ labels,
        const float* __restrict__ protos, const int* __restrict__ plabels,
        float* __restrict__ rowE,
        int* __restrict__ nfpart, int* __restrict__ nf,
        float* __restrict__ Psum, float* __restrict__ expPsum,
        float* __restrict__ PLab, float* __restrict__ gpart,
        unsigned short* ldsB, float (*colE)[256],
        float* novR, float* novC, int* plabL, int* labRow, float* redD) {
    const int tid = threadIdx.x;            // 0..511
    const int wv = tid >> 6, lane = tid & 63;
    const int quad = lane >> 4, cq = lane & 15;

    if (tid < B_PRO) plabL[tid] = plabels[tid];

    // A fragments straight from f32 feat, converted in registers:
    // rows R0 + wv*32 + mt*16 + cq, k = ks*32 + quad*8 .. +7
    short8 afr[2][4];
    #pragma unroll
    for (int mt = 0; mt < 2; ++mt)
        #pragma unroll
        for (int ks = 0; ks < 4; ++ks) {
            const float* s = feat + (size_t)(R0 + wv * 32 + mt * 16 + cq) * K_DIM
                             + ks * 32 + quad * 8;
            float4 x = ((const float4*)s)[0];
            float4 y = ((const float4*)s)[1];
            afr[mt][ks] = pack8(x, y);
        }
    __syncthreads();   // plabL visible

    // novelty: 256 rows + 256 cols, one entry per thread
    {
        const int g = (tid < 256) ? (R0 + tid) : (C0 + (tid - 256));
        const int lbl = labels[g];
        int m = 0;
        #pragma unroll 4
        for (int j = 0; j < B_PRO; ++j) m |= (plabL[j] == lbl);
        const float nv = m ? 0.f : 1.f;
        if (tid < 256) { novR[tid] = nv; labRow[tid] = lbl; }
        else novC[tid - 256] = nv;
    }
    __syncthreads();   // novR/novC visible

    float nmR[2][4];
    #pragma unroll
    for (int mt = 0; mt < 2; ++mt)
        #pragma unroll
        for (int r = 0; r < 4; ++r)
            nmR[mt][r] = novR[wv * 32 + mt * 16 + quad * 4 + r];
    float nmcA[16];
    #pragma unroll
    for (int c2 = 0; c2 < 16; ++c2)
        nmcA[c2] = novC[c2 * 16 + cq];

    float accE[2][4];
    #pragma unroll
    for (int mt = 0; mt < 2; ++mt)
        #pragma unroll
        for (int r = 0; r < 4; ++r) accE[mt][r] = 0.f;

    float g_acc = 0.f;                       // DIAG: novel-masked colsum elem

    const int rbase = R0 + wv * 32 + quad * 4;   // DIAG row index helper

    #pragma unroll 1
    for (int half = 0; half < 2; ++half) {
        // stage cols [C0 + half*128, +128) as bf16(C*f) into LDS (4/thread)
        for (int e = tid; e < 2048; e += 512) {
            const int col = e >> 4, sg = e & 15;
            const float* s = feat + (size_t)(C0 + half * 128 + col) * K_DIM + sg * 8;
            float4 x = ((const float4*)s)[0];
            float4 y = ((const float4*)s)[1];
            ushort4 o0 = make_ushort4(f2bf(x.x*C_SCALE), f2bf(x.y*C_SCALE),
                                      f2bf(x.z*C_SCALE), f2bf(x.w*C_SCALE));
            ushort4 o1 = make_ushort4(f2bf(y.x*C_SCALE), f2bf(y.y*C_SCALE),
                                      f2bf(y.z*C_SCALE), f2bf(y.w*C_SCALE));
            *(ushort4*)&ldsB[col * BS + sg * 8]     = o0;
            *(ushort4*)&ldsB[col * BS + sg * 8 + 4] = o1;
        }
        __syncthreads();   // staging visible

        #pragma unroll 2
        for (int ct8 = 0; ct8 < 8; ++ct8) {
            const int ct = half * 8 + ct8;
            const unsigned short* bp = &ldsB[(ct8 * 16 + cq) * BS + quad * 8];
            short8 b0 = *(const short8*)(bp);
            short8 b1 = *(const short8*)(bp + 32);
            short8 b2 = *(const short8*)(bp + 64);
            short8 b3 = *(const short8*)(bp + 96);

            floatx4 D0 = (floatx4){0.f, 0.f, 0.f, 0.f};
            floatx4 D1 = (floatx4){0.f, 0.f, 0.f, 0.f};
            D0 = __builtin_amdgcn_mfma_f32_16x16x32_bf16(afr[0][0], b0, D0, 0, 0, 0);
            D0 = __builtin_amdgcn_mfma_f32_16x16x32_bf16(afr[0][1], b1, D0, 0, 0, 0);
            D0 = __builtin_amdgcn_mfma_f32_16x16x32_bf16(afr[0][2], b2, D0, 0, 0, 0);
            D0 = __builtin_amdgcn_mfma_f32_16x16x32_bf16(afr[0][3], b3, D0, 0, 0, 0);
            D1 = __builtin_amdgcn_mfma_f32_16x16x32_bf16(afr[1][0], b0, D1, 0, 0, 0);
            D1 = __builtin_amdgcn_mfma_f32_16x16x32_bf16(afr[1][1], b1, D1, 0, 0, 0);
            D1 = __builtin_amdgcn_mfma_f32_16x16x32_bf16(afr[1][2], b2, D1, 0, 0, 0);
            D1 = __builtin_amdgcn_mfma_f32_16x16x32_bf16(afr[1][3], b3, D1, 0, 0, 0);

            const float nmc = nmcA[ct];
            float cpE = 0.f;
            #pragma unroll
            for (int r = 0; r < 4; ++r) {
                float e0 = EXP2(D0[r]), e1 = EXP2(D1[r]);
                if (DIAG) {
                    const int colg = C0 + ct * 16 + cq;
                    if (rbase + r == colg) e0 = 0.f;
                    if (rbase + 16 + r == colg) e1 = 0.f;
                }
                accE[0][r] += e0 * nmc;  cpE += e0 * nmR[0][r];
                accE[1][r] += e1 * nmc;  cpE += e1 * nmR[1][r];
            }
            cpE += __shfl_xor(cpE, 16); cpE += __shfl_xor(cpE, 32);
            if (quad == 0) colE[wv][ct * 16 + cq] = cpE;
        }

        if (DIAG && tid < 128) {
            // novel-masked colsum of this phase's staged tile: g element tid
            float s = 0.f;
            #pragma unroll 4
            for (int c2 = 0; c2 < 128; ++c2)
                s += novC[half * 128 + c2] * bf2f(ldsB[c2 * BS + tid]);
            g_acc += s;
        }
        __syncthreads();   // reads done before restage; publishes colE
    }

    // row sums: reduce over the 16 cq lanes, write slot b
    #pragma unroll
    for (int mt = 0; mt < 2; ++mt)
        #pragma unroll
        for (int r = 0; r < 4; ++r) {
            float e = accE[mt][r];
            e += __shfl_xor(e, 1); e += __shfl_xor(e, 2);
            e += __shfl_xor(e, 4); e += __shfl_xor(e, 8);
            accE[mt][r] = e;
        }
    if (cq == 0) {
        const size_t slotR = (size_t)b * M_TOT;
        #pragma unroll
        for (int mt = 0; mt < 2; ++mt)
            #pragma unroll
            for (int r = 0; r < 4; ++r) {
                const int rowg = R0 + wv * 32 + mt * 16 + quad * 4 + r;
                rowE[slotR + rowg] = accE[mt][r];
            }
    }

    if (!DIAG) {
        // col side -> slot a (colE published by the half-loop-end sync)
        if (tid < 256) {
            float ce = 0.f;
            #pragma unroll
            for (int w = 0; w < 8; ++w) ce += colE[w][tid];
            rowE[(size_t)a * M_TOT + C0 + tid] = ce;
        }
    } else {
        // ---- diag-only epilogue: g / nf / nfpart + proto GEMM ----
        if (tid < 128) gpart[a * 128 + tid] = g_acc;
        {
            float nvv = (tid < 256) ? novR[tid] : 0.f;
            for (int off = 1; off < 64; off <<= 1) nvv += __shfl_xor(nvv, off);
            if (lane == 0) redD[wv] = nvv;
        }
        if (tid < 256) nf[R0 + tid] = (int)novR[tid];

        // re-stage protos into ldsB (main-loop reads drained by the last sync)
        for (int idx = tid; idx < 3200; idx += 512) {
            const int pr = idx >> 5, sg = idx & 31;
            float4 v = ((const float4*)protos)[idx];
            *(ushort4*)&ldsB[pr * BS + sg * 4] =
                make_ushort4(f2bf(v.x), f2bf(v.y), f2bf(v.z), f2bf(v.w));
        }
        for (int idx = tid; idx < 384; idx += 512) {   // zero rows 100..111
            const int pr = B_PRO + (idx >> 5), sg = idx & 31;
            *(ushort4*)&ldsB[pr * BS + sg * 4] = make_ushort4(0, 0, 0, 0);
        }
        __syncthreads();

        if (tid == 0) {
            float c = 0.f;
            #pragma unroll
            for (int w = 0; w < 8; ++w) c += redD[w];
            nfpart[a] = (int)c;
        }

        float ps2[2][4], es2[2][4], pl2[2][4];
        #pragma unroll
        for (int mt = 0; mt < 2; ++mt)
            #pragma unroll
            for (int r = 0; r < 4; ++r) { ps2[mt][r]=0.f; es2[mt][r]=0.f; pl2[mt][r]=0.f; }

        #pragma unroll 1
        for (int g = 0; g < 7; ++g) {
            const unsigned short* bp = &ldsB[(g * 16 + cq) * BS + quad * 8];
            short8 b0 = *(const short8*)(bp);
            short8 b1 = *(const short8*)(bp + 32);
            short8 b2 = *(const short8*)(bp + 64);
            short8 b3 = *(const short8*)(bp + 96);
            floatx4 E0 = (floatx4){0.f, 0.f, 0.f, 0.f};
            floatx4 E1 = (floatx4){0.f, 0.f, 0.f, 0.f};
            E0 = __builtin_amdgcn_mfma_f32_16x16x32_bf16(afr[0][0], b0, E0, 0, 0, 0);
            E0 = __builtin_amdgcn_mfma_f32_16x16x32_bf16(afr[0][1], b1, E0, 0, 0, 0);
            E0 = __builtin_amdgcn_mfma_f32_16x16x32_bf16(afr[0][2], b2, E0, 0, 0, 0);
            E0 = __builtin_amdgcn_mfma_f32_16x16x32_bf16(afr[0][3], b3, E0, 0, 0, 0);
            E1 = __builtin_amdgcn_mfma_f32_16x16x32_bf16(afr[1][0], b0, E1, 0, 0, 0);
            E1 = __builtin_amdgcn_mfma_f32_16x16x32_bf16(afr[1][1], b1, E1, 0, 0, 0);
            E1 = __builtin_amdgcn_mfma_f32_16x16x32_bf16(afr[1][2], b2, E1, 0, 0, 0);
            E1 = __builtin_amdgcn_mfma_f32_16x16x32_bf16(afr[1][3], b3, E1, 0, 0, 0);
            const int bcol = g * 16 + cq;
            if (bcol < B_PRO) {
                #pragma unroll
                for (int r = 0; r < 4; ++r) {
                    const float Pv0 = E0[r] * INV_T;
                    ps2[0][r] += Pv0; es2[0][r] += __expf(Pv0);
                    if (bcol == labRow[wv * 32 + quad * 4 + r]) pl2[0][r] += Pv0;
                    const float Pv1 = E1[r] * INV_T;
                    ps2[1][r] += Pv1; es2[1][r] += __expf(Pv1);
                    if (bcol == labRow[wv * 32 + 16 + quad * 4 + r]) pl2[1][r] += Pv1;
                }
            }
        }
        #pragma unroll
        for (int mt = 0; mt < 2; ++mt)
            #pragma unroll
            for (int r = 0; r < 4; ++r) {
                float p = ps2[mt][r], e = es2[mt][r], l = pl2[mt][r];
                p += __shfl_xor(p, 1); p += __shfl_xor(p, 2);
                p += __shfl_xor(p, 4); p += __shfl_xor(p, 8);
                e += __shfl_xor(e, 1); e += __shfl_xor(e, 2);
                e += __shfl_xor(e, 4); e += __shfl_xor(e, 8);
                l += __shfl_xor(l, 1); l += __shfl_xor(l, 2);
                l += __shfl_xor(l, 4); l += __shfl_xor(l, 8);
                if (cq == 0) {
                    const int rowg = R0 + wv * 32 + mt * 16 + quad * 4 + r;
                    Psum[rowg] = p; expPsum[rowg] = e; PLab[rowg] = l;
                }
            }
    }
}

// ---------------------------------------------------------------- k_fused
// 528 blocks x 512 thr, normal launch. Phase 1 = tile work. Each block then
// takes a ticket; the last 64 finishers spin until all 528 are done, acquire,
// and run one 128-row slice of the loss assembly.
__global__ __launch_bounds__(512, 4) void k_fused(
        const float* __restrict__ feat, const int* __restrict__ labels,
        const float* __restrict__ protos, const int* __restrict__ plabels,
        float* __restrict__ rowE,
        int* __restrict__ nfpart, int* __restrict__ nf,
        float* __restrict__ Psum, float* __restrict__ expPsum,
        float* __restrict__ PLab, float* __restrict__ gpart,
        float* __restrict__ out) {
    __shared__ unsigned short ldsB[128 * BS];    // 34816 B (reused for protos)
    __shared__ float colE[8][256];               // 8192 B
    __shared__ float novR[256];                  // 1024 B
    __shared__ float novC[256];                  // 1024 B (reused as g[] later)
    __shared__ int plabL[B_PRO];                 // 400 B
    __shared__ int labRow[256];                  // 1024 B
    __shared__ float redD[8];                    // 32 B
    __shared__ int ticket;
    __shared__ int shNn;

    const int tid = threadIdx.x;
    if (blockIdx.x == 0 && tid == 0) out[0] = 0.f;   // released by fence below

    const int id = blockIdx.x;
    if (id < NT) {
        sym_body<true>(id, id, id * RT, id * RT,
                       feat, labels, protos, plabels, rowE,
                       nfpart, nf, Psum, expPsum, PLab, gpart,
                       ldsB, colE, novR, novC, plabL, labRow, redD);
    } else {
        const int p = id - NT;
        int aa = 0, rem = p;
        while (rem >= NT - 1 - aa) { rem -= (NT - 1 - aa); ++aa; }
        const int bb2 = aa + 1 + rem;
        sym_body<false>(aa, bb2, aa * RT, bb2 * RT,
                        feat, labels, protos, plabels, rowE,
                        nfpart, nf, Psum, expPsum, PLab, gpart,
                        ldsB, colE, novR, novC, plabL, labRow, redD);
    }

    // ---- release + ticket ----
    __threadfence();                       // device-scope release of all writes
    __syncthreads();
    if (tid == 0) ticket = atomicAdd(&g_counter, 1);
    __syncthreads();
    const int t = ticket;
    const int base = (t / NBLK) * NBLK;    // monotonic epochs: no reset needed
    const int rank = t - base;
    if (rank < NBLK - NTAIL) return;       // non-tail: done
    const int slice = rank - (NBLK - NTAIL);

    // ---- tail: wait for all blocks, acquire ----
    if (tid == 0) {
        const int target = base + NBLK;
        while (atomicAdd(&g_counter, 0) < target) __builtin_amdgcn_s_sleep(2);
    }
    __syncthreads();
    __threadfence();                       // device-scope acquire

    // ---------------- phase 2: loss assembly, 128 rows/slice ----------------
    if (tid < 128) {                       // g = colsum of gpart (reuse novC)
        float s = 0.f;
        #pragma unroll 4
        for (int a2 = 0; a2 < 32; ++a2) s += gpart[a2 * 128 + tid];
        novC[tid] = s;
    }
    if (tid < 32) {
        int c = nfpart[tid];
        for (int off = 1; off < 32; off <<= 1) c += __shfl_xor(c, off);
        if (tid == 0) shNn = c;
    }
    __syncthreads();

    const int rp = tid >> 2, u = tid & 3;  // 128 rows, 4 lanes each
    const int i = slice * 128 + rp;

    float ep = 0.f;
    #pragma unroll
    for (int s = u; s < 32; s += 4) ep += rowE[(size_t)s * M_TOT + i];

    const float* fr = feat + (size_t)i * K_DIM;
    float sZ = 0.f, dd = 0.f;
    #pragma unroll
    for (int k4 = u * 8; k4 < u * 8 + 8; ++k4) {
        float4 v = ((const float4*)fr)[k4];
        const float fb0 = bf2f(f2bf(v.x)), fc0 = bf2f(f2bf(v.x * C_SCALE));
        const float fb1 = bf2f(f2bf(v.y)), fc1 = bf2f(f2bf(v.y * C_SCALE));
        const float fb2 = bf2f(f2bf(v.z)), fc2 = bf2f(f2bf(v.z * C_SCALE));
        const float fb3 = bf2f(f2bf(v.w)), fc3 = bf2f(f2bf(v.w * C_SCALE));
        const float* gv = &novC[k4 * 4];
        sZ += fb0 * gv[0]; dd += fb0 * fc0;
        sZ += fb1 * gv[1]; dd += fb1 * fc1;
        sZ += fb2 * gv[2]; dd += fb2 * fc2;
        sZ += fb3 * gv[3]; dd += fb3 * fc3;
    }
    ep += __shfl_xor(ep, 1); ep += __shfl_xor(ep, 2);
    sZ += __shfl_xor(sZ, 1); sZ += __shfl_xor(sZ, 2);
    dd += __shfl_xor(dd, 1); dd += __shfl_xor(dd, 2);

    float contrib = 0.f;
    if (u == 0) {
        const int Nn = shNn;
        if (nf[i]) {
            const float cnt = (float)(Nn - 1);
            const float denom = ep + Psum[i];    // + RAW proto logit sum (faithful)
            const float sp = sZ - dd;            // sum_{j novel, j!=i} D_ij
            const float num = sp * LN2 - logf(denom) * cnt;
            const float sc = cnt > 0.f ? cnt : 1.f;
            contrib = -(num / sc);
        } else {
            contrib = -(PLab[i] - logf(ep + expPsum[i]));
        }
    }
    // wave-reduce (non-u0 lanes contribute 0)
    for (int off = 1; off < 64; off <<= 1) contrib += __shfl_xor(contrib, off);
    if ((tid & 63) == 0) redD[tid >> 6] = contrib;
    __syncthreads();
    if (tid == 0) {
        float s = 0.f;
        #pragma unroll
        for (int w = 0; w < 8; ++w) s += redD[w];
        atomicAdd(out, s * (1.0f / (float)M_TOT));
    }
}

// ---------------------------------------------------------------- launch
extern "C" void kernel_launch(void* const* d_in, const int* in_sizes, int n_in,
                              void* d_out, int out_size, void* d_ws, size_t ws_size,
                              hipStream_t stream) {
    const float* feat    = (const float*)d_in[0];
    const int*   labels  = (const int*)d_in[1];
    const float* protos  = (const float*)d_in[2];
    const int*   plabels = (const int*)d_in[3];
    float* out = (float*)d_out;

    char* ws = (char*)d_ws;
    float* rowE    = (float*)ws;                     // 32 x 8192 fp32 (1 MB)
    int*   nfpart  = (int*)(ws + 1048576);           // 32 ints
    int*   nf      = (int*)(ws + 1052672);           // 8192 ints
    float* Psum    = (float*)(ws + 1085440);
    float* expPsum = (float*)(ws + 1118208);
    float* PLab    = (float*)(ws + 1150976);
    float* gpart   = (float*)(ws + 1183744);         // 32 x 128 fp32

    k_fused<<<NBLK, 512, 0, stream>>>(feat, labels, protos, plabels,
                                      rowE, nfpart, nf,
                                      Psum, expPsum, PLab, gpart, out);
}

// Round 12
// 101.091 us; speedup vs baseline: 1.9636x; 1.9636x over previous
//
#include <hip/hip_runtime.h>
#include <stdint.h>

// SupConLossWithPrototype on MI355X.
// Round 23: REVERT to the round-20/R9 kernel (best passing: 101.4us total,
// k_sym < 40us). Both fusion mechanisms are falsified on this harness:
// cooperative launch silently no-ops under graph capture (R10, absmax=|loss|);
// ticket-counter busy-wait fusion runs 3.4x slow (R11: 141us, all pipes
// scaled down uniformly => ~100us of in-kernel spin).
// Final budget: poison-fill 41.6us (256MiB @ ~80% HBM peak, harness-serial,
// uncontrollable) + k_sym ~38-40us (latency floor: 10 structural variants
// 38-44us) + k_final ~4us + ~15us dispatch overhead.

#define M_TOT 8192
#define K_DIM 128
#define B_PRO 100
#define INV_T 5.0f                          // 1/TEMP
#define C_SCALE 7.2134752044448170f         // 5 * log2(e)
#define LN2    0.6931471805599453f
#define RT    256                           // tile side
#define NT    (M_TOT / RT)                  // 32 row/col groups
#define NPAIR (NT * (NT - 1) / 2)           // 496 strict upper pairs
#define NBLK  (NT + NPAIR)                  // 528 blocks
#define BS    136                           // B/proto LDS stride (bf16 elems)
#define PB    112                           // padded proto rows (7 groups of 16)

#if __has_builtin(__builtin_amdgcn_exp2f)
#define EXP2(x) __builtin_amdgcn_exp2f(x)
#else
#define EXP2(x) __expf((x) * 0.6931471805599453f)
#endif

typedef __attribute__((ext_vector_type(8))) short  short8;   // 8 bf16 (MFMA A/B frag)
typedef __attribute__((ext_vector_type(4))) float  floatx4;  // MFMA C/D frag

__device__ __forceinline__ float bf2f(unsigned short u) {
    union { unsigned int i; float f; } v; v.i = ((unsigned int)u) << 16; return v.f;
}
// HW RNE convert: compiler emits v_cvt_pk_bf16_f32 for paired uses.
__device__ __forceinline__ unsigned short f2bf(float x) {
    __bf16 b = (__bf16)x;
    return __builtin_bit_cast(unsigned short, b);
}
__device__ __forceinline__ short8 pack8(float4 a, float4 b) {
    short8 r;
    r[0] = (short)f2bf(a.x); r[1] = (short)f2bf(a.y);
    r[2] = (short)f2bf(a.z); r[3] = (short)f2bf(a.w);
    r[4] = (short)f2bf(b.x); r[5] = (short)f2bf(b.y);
    r[6] = (short)f2bf(b.z); r[7] = (short)f2bf(b.w);
    return r;
}

// ---------------------------------------------------------------- k_sym body
// One 256x256 tile, 512 threads (8 waves x 32 rows). Operands converted
// in-block from f32 feat; B staged to LDS bf16(C*f) in two 128-col phases.
// accE = sum exp2(D)*mask, row and col direction (raw-logit sums via the
// g-trick in k_final). DIAG excludes row==col exactly, accumulates the
// novel-masked colsum of its staged tile into gpart, and afterwards computes
// the proto GEMM for its 256 rows (reusing afr + ldsB).
template<bool DIAG>
__device__ __forceinline__ void sym_body(
        int a, int b, int R0, int C0,
        const float* __restrict__ feat, const int* __restrict__ labels,
        const float* __restrict__ protos, const int* __restrict__ plabels,
        float* __restrict__ rowE,
        int* __restrict__ nfpart, int* __restrict__ nf,
        float* __restrict__ Psum, float* __restrict__ expPsum,
        float* __restrict__ PLab, float* __restrict__ gpart,
        unsigned short* ldsB, float (*colE)[256],
        float* novR, float* novC, int* plabL, int* labRow, float* redD) {
    const int tid = threadIdx.x;            // 0..511
    const int wv = tid >> 6, lane = tid & 63;
    const int quad = lane >> 4, cq = lane & 15;

    if (tid < B_PRO) plabL[tid] = plabels[tid];

    // A fragments straight from f32 feat, converted in registers:
    // rows R0 + wv*32 + mt*16 + cq, k = ks*32 + quad*8 .. +7
    short8 afr[2][4];
    #pragma unroll
    for (int mt = 0; mt < 2; ++mt)
        #pragma unroll
        for (int ks = 0; ks < 4; ++ks) {
            const float* s = feat + (size_t)(R0 + wv * 32 + mt * 16 + cq) * K_DIM
                             + ks * 32 + quad * 8;
            float4 x = ((const float4*)s)[0];
            float4 y = ((const float4*)s)[1];
            afr[mt][ks] = pack8(x, y);
        }
    __syncthreads();   // plabL visible

    // novelty: 256 rows + 256 cols, one entry per thread
    {
        const int g = (tid < 256) ? (R0 + tid) : (C0 + (tid - 256));
        const int lbl = labels[g];
        int m = 0;
        #pragma unroll 4
        for (int j = 0; j < B_PRO; ++j) m |= (plabL[j] == lbl);
        const float nv = m ? 0.f : 1.f;
        if (tid < 256) { novR[tid] = nv; labRow[tid] = lbl; }
        else novC[tid - 256] = nv;
    }
    __syncthreads();   // novR/novC visible

    float nmR[2][4];
    #pragma unroll
    for (int mt = 0; mt < 2; ++mt)
        #pragma unroll
        for (int r = 0; r < 4; ++r)
            nmR[mt][r] = novR[wv * 32 + mt * 16 + quad * 4 + r];
    float nmcA[16];
    #pragma unroll
    for (int c2 = 0; c2 < 16; ++c2)
        nmcA[c2] = novC[c2 * 16 + cq];

    float accE[2][4];
    #pragma unroll
    for (int mt = 0; mt < 2; ++mt)
        #pragma unroll
        for (int r = 0; r < 4; ++r) accE[mt][r] = 0.f;

    float g_acc = 0.f;                       // DIAG: novel-masked colsum elem

    const int rbase = R0 + wv * 32 + quad * 4;   // DIAG row index helper

    #pragma unroll 1
    for (int half = 0; half < 2; ++half) {
        // stage cols [C0 + half*128, +128) as bf16(C*f) into LDS (4/thread)
        for (int e = tid; e < 2048; e += 512) {
            const int col = e >> 4, sg = e & 15;
            const float* s = feat + (size_t)(C0 + half * 128 + col) * K_DIM + sg * 8;
            float4 x = ((const float4*)s)[0];
            float4 y = ((const float4*)s)[1];
            ushort4 o0 = make_ushort4(f2bf(x.x*C_SCALE), f2bf(x.y*C_SCALE),
                                      f2bf(x.z*C_SCALE), f2bf(x.w*C_SCALE));
            ushort4 o1 = make_ushort4(f2bf(y.x*C_SCALE), f2bf(y.y*C_SCALE),
                                      f2bf(y.z*C_SCALE), f2bf(y.w*C_SCALE));
            *(ushort4*)&ldsB[col * BS + sg * 8]     = o0;
            *(ushort4*)&ldsB[col * BS + sg * 8 + 4] = o1;
        }
        __syncthreads();   // staging visible

        #pragma unroll 2
        for (int ct8 = 0; ct8 < 8; ++ct8) {
            const int ct = half * 8 + ct8;
            const unsigned short* bp = &ldsB[(ct8 * 16 + cq) * BS + quad * 8];
            short8 b0 = *(const short8*)(bp);
            short8 b1 = *(const short8*)(bp + 32);
            short8 b2 = *(const short8*)(bp + 64);
            short8 b3 = *(const short8*)(bp + 96);

            floatx4 D0 = (floatx4){0.f, 0.f, 0.f, 0.f};
            floatx4 D1 = (floatx4){0.f, 0.f, 0.f, 0.f};
            D0 = __builtin_amdgcn_mfma_f32_16x16x32_bf16(afr[0][0], b0, D0, 0, 0, 0);
            D0 = __builtin_amdgcn_mfma_f32_16x16x32_bf16(afr[0][1], b1, D0, 0, 0, 0);
            D0 = __builtin_amdgcn_mfma_f32_16x16x32_bf16(afr[0][2], b2, D0, 0, 0, 0);
            D0 = __builtin_amdgcn_mfma_f32_16x16x32_bf16(afr[0][3], b3, D0, 0, 0, 0);
            D1 = __builtin_amdgcn_mfma_f32_16x16x32_bf16(afr[1][0], b0, D1, 0, 0, 0);
            D1 = __builtin_amdgcn_mfma_f32_16x16x32_bf16(afr[1][1], b1, D1, 0, 0, 0);
            D1 = __builtin_amdgcn_mfma_f32_16x16x32_bf16(afr[1][2], b2, D1, 0, 0, 0);
            D1 = __builtin_amdgcn_mfma_f32_16x16x32_bf16(afr[1][3], b3, D1, 0, 0, 0);

            const float nmc = nmcA[ct];
            float cpE = 0.f;
            #pragma unroll
            for (int r = 0; r < 4; ++r) {
                float e0 = EXP2(D0[r]), e1 = EXP2(D1[r]);
                if (DIAG) {
                    const int colg = C0 + ct * 16 + cq;
                    if (rbase + r == colg) e0 = 0.f;
                    if (rbase + 16 + r == colg) e1 = 0.f;
                }
                accE[0][r] += e0 * nmc;  cpE += e0 * nmR[0][r];
                accE[1][r] += e1 * nmc;  cpE += e1 * nmR[1][r];
            }
            cpE += __shfl_xor(cpE, 16); cpE += __shfl_xor(cpE, 32);
            if (quad == 0) colE[wv][ct * 16 + cq] = cpE;
        }

        if (DIAG && tid < 128) {
            // novel-masked colsum of this phase's staged tile: g element tid
            float s = 0.f;
            #pragma unroll 4
            for (int c2 = 0; c2 < 128; ++c2)
                s += novC[half * 128 + c2] * bf2f(ldsB[c2 * BS + tid]);
            g_acc += s;
        }
        __syncthreads();   // reads done before restage; publishes colE
    }

    // row sums: reduce over the 16 cq lanes, write slot b
    #pragma unroll
    for (int mt = 0; mt < 2; ++mt)
        #pragma unroll
        for (int r = 0; r < 4; ++r) {
            float e = accE[mt][r];
            e += __shfl_xor(e, 1); e += __shfl_xor(e, 2);
            e += __shfl_xor(e, 4); e += __shfl_xor(e, 8);
            accE[mt][r] = e;
        }
    if (cq == 0) {
        const size_t slotR = (size_t)b * M_TOT;
        #pragma unroll
        for (int mt = 0; mt < 2; ++mt)
            #pragma unroll
            for (int r = 0; r < 4; ++r) {
                const int rowg = R0 + wv * 32 + mt * 16 + quad * 4 + r;
                rowE[slotR + rowg] = accE[mt][r];
            }
    }

    if (!DIAG) {
        // col side -> slot a (colE published by the half-loop-end sync)
        if (tid < 256) {
            float ce = 0.f;
            #pragma unroll
            for (int w = 0; w < 8; ++w) ce += colE[w][tid];
            rowE[(size_t)a * M_TOT + C0 + tid] = ce;
        }
    } else {
        // ---- diag-only epilogue: g / nf / nfpart + proto GEMM ----
        if (tid < 128) gpart[a * 128 + tid] = g_acc;
        {
            float nvv = (tid < 256) ? novR[tid] : 0.f;
            for (int off = 1; off < 64; off <<= 1) nvv += __shfl_xor(nvv, off);
            if (lane == 0) redD[wv] = nvv;
        }
        if (tid < 256) nf[R0 + tid] = (int)novR[tid];

        // re-stage protos into ldsB (main-loop reads drained by the last sync)
        for (int idx = tid; idx < 3200; idx += 512) {
            const int pr = idx >> 5, sg = idx & 31;
            float4 v = ((const float4*)protos)[idx];
            *(ushort4*)&ldsB[pr * BS + sg * 4] =
                make_ushort4(f2bf(v.x), f2bf(v.y), f2bf(v.z), f2bf(v.w));
        }
        for (int idx = tid; idx < 384; idx += 512) {   // zero rows 100..111
            const int pr = B_PRO + (idx >> 5), sg = idx & 31;
            *(ushort4*)&ldsB[pr * BS + sg * 4] = make_ushort4(0, 0, 0, 0);
        }
        __syncthreads();

        if (tid == 0) {
            float c = 0.f;
            #pragma unroll
            for (int w = 0; w < 8; ++w) c += redD[w];
            nfpart[a] = (int)c;
        }

        float ps2[2][4], es2[2][4], pl2[2][4];
        #pragma unroll
        for (int mt = 0; mt < 2; ++mt)
            #pragma unroll
            for (int r = 0; r < 4; ++r) { ps2[mt][r]=0.f; es2[mt][r]=0.f; pl2[mt][r]=0.f; }

        #pragma unroll 1
        for (int g = 0; g < 7; ++g) {
            const unsigned short* bp = &ldsB[(g * 16 + cq) * BS + quad * 8];
            short8 b0 = *(const short8*)(bp);
            short8 b1 = *(const short8*)(bp + 32);
            short8 b2 = *(const short8*)(bp + 64);
            short8 b3 = *(const short8*)(bp + 96);
            floatx4 E0 = (floatx4){0.f, 0.f, 0.f, 0.f};
            floatx4 E1 = (floatx4){0.f, 0.f, 0.f, 0.f};
            E0 = __builtin_amdgcn_mfma_f32_16x16x32_bf16(afr[0][0], b0, E0, 0, 0, 0);
            E0 = __builtin_amdgcn_mfma_f32_16x16x32_bf16(afr[0][1], b1, E0, 0, 0, 0);
            E0 = __builtin_amdgcn_mfma_f32_16x16x32_bf16(afr[0][2], b2, E0, 0, 0, 0);
            E0 = __builtin_amdgcn_mfma_f32_16x16x32_bf16(afr[0][3], b3, E0, 0, 0, 0);
            E1 = __builtin_amdgcn_mfma_f32_16x16x32_bf16(afr[1][0], b0, E1, 0, 0, 0);
            E1 = __builtin_amdgcn_mfma_f32_16x16x32_bf16(afr[1][1], b1, E1, 0, 0, 0);
            E1 = __builtin_amdgcn_mfma_f32_16x16x32_bf16(afr[1][2], b2, E1, 0, 0, 0);
            E1 = __builtin_amdgcn_mfma_f32_16x16x32_bf16(afr[1][3], b3, E1, 0, 0, 0);
            const int bcol = g * 16 + cq;
            if (bcol < B_PRO) {
                #pragma unroll
                for (int r = 0; r < 4; ++r) {
                    const float Pv0 = E0[r] * INV_T;
                    ps2[0][r] += Pv0; es2[0][r] += __expf(Pv0);
                    if (bcol == labRow[wv * 32 + quad * 4 + r]) pl2[0][r] += Pv0;
                    const float Pv1 = E1[r] * INV_T;
                    ps2[1][r] += Pv1; es2[1][r] += __expf(Pv1);
                    if (bcol == labRow[wv * 32 + 16 + quad * 4 + r]) pl2[1][r] += Pv1;
                }
            }
        }
        #pragma unroll
        for (int mt = 0; mt < 2; ++mt)
            #pragma unroll
            for (int r = 0; r < 4; ++r) {
                float p = ps2[mt][r], e = es2[mt][r], l = pl2[mt][r];
                p += __shfl_xor(p, 1); p += __shfl_xor(p, 2);
                p += __shfl_xor(p, 4); p += __shfl_xor(p, 8);
                e += __shfl_xor(e, 1); e += __shfl_xor(e, 2);
                e += __shfl_xor(e, 4); e += __shfl_xor(e, 8);
                l += __shfl_xor(l, 1); l += __shfl_xor(l, 2);
                l += __shfl_xor(l, 4); l += __shfl_xor(l, 8);
                if (cq == 0) {
                    const int rowg = R0 + wv * 32 + mt * 16 + quad * 4 + r;
                    Psum[rowg] = p; expPsum[rowg] = e; PLab[rowg] = l;
                }
            }
    }
}

// ---------------------------------------------------------------- k_sym
// 528 blocks x 512 thr. Blocks 0..31: diagonal tiles (also g colsum + proto
// GEMM for their 256 rows). Blocks 32..527: strict-upper pairs. Block 0
// zeroes out[0].
__global__ __launch_bounds__(512, 4) void k_sym(
        const float* __restrict__ feat, const int* __restrict__ labels,
        const float* __restrict__ protos, const int* __restrict__ plabels,
        float* __restrict__ rowE,
        int* __restrict__ nfpart, int* __restrict__ nf,
        float* __restrict__ Psum, float* __restrict__ expPsum,
        float* __restrict__ PLab, float* __restrict__ gpart,
        float* __restrict__ out) {
    __shared__ unsigned short ldsB[128 * BS];    // 34816 B (reused for protos)
    __shared__ float colE[8][256];               // 8192 B
    __shared__ float novR[256];                  // 1024 B
    __shared__ float novC[256];                  // 1024 B
    __shared__ int plabL[B_PRO];                 // 400 B
    __shared__ int labRow[256];                  // 1024 B
    __shared__ float redD[8];                    // 32 B

    if (blockIdx.x == 0 && threadIdx.x == 0) out[0] = 0.f;

    const int id = blockIdx.x;
    if (id < NT) {
        sym_body<true>(id, id, id * RT, id * RT,
                       feat, labels, protos, plabels, rowE,
                       nfpart, nf, Psum, expPsum, PLab, gpart,
                       ldsB, colE, novR, novC, plabL, labRow, redD);
    } else {
        const int p = id - NT;
        int aa = 0, rem = p;
        while (rem >= NT - 1 - aa) { rem -= (NT - 1 - aa); ++aa; }
        const int bb2 = aa + 1 + rem;
        sym_body<false>(aa, bb2, aa * RT, bb2 * RT,
                        feat, labels, protos, plabels, rowE,
                        nfpart, nf, Psum, expPsum, PLab, gpart,
                        ldsB, colE, novR, novC, plabL, labRow, redD);
    }
}

// ---------------------------------------------------------------- k_final
// 64 blocks x 128 thr, one row per thread. g assembled from gpart (32x128);
// per row: ep = 32 slot loads; sZ = dot(fb,g); dd = dot(fb,fc); loss formula
// (sp = sZ - dd).
__global__ __launch_bounds__(128) void k_final(
        const float* __restrict__ feat,
        const float* __restrict__ rowE,
        const float* __restrict__ Psum, const float* __restrict__ expPsum,
        const float* __restrict__ PLab, const int* __restrict__ nf,
        const int* __restrict__ nfpart, const float* __restrict__ gpart,
        float* __restrict__ out) {
    __shared__ float g[128];
    __shared__ int shNn;
    __shared__ float red[2];
    const int tid = threadIdx.x;
    const int i = blockIdx.x * 128 + tid;

    {
        float s = 0.f;
        #pragma unroll 4
        for (int a2 = 0; a2 < 32; ++a2) s += gpart[a2 * 128 + tid];
        g[tid] = s;
    }
    if (tid < 32) {
        int c = nfpart[tid];
        for (int off = 1; off < 32; off <<= 1) c += __shfl_xor(c, off);
        if (tid == 0) shNn = c;
    }
    __syncthreads();

    // ep: 32 slots, slot-major (coalesced across threads)
    float e0 = 0.f, e1 = 0.f, e2 = 0.f, e3 = 0.f;
    #pragma unroll
    for (int s = 0; s < 8; ++s) {
        e0 += rowE[(size_t)(4 * s + 0) * M_TOT + i];
        e1 += rowE[(size_t)(4 * s + 1) * M_TOT + i];
        e2 += rowE[(size_t)(4 * s + 2) * M_TOT + i];
        e3 += rowE[(size_t)(4 * s + 3) * M_TOT + i];
    }
    const float ep = (e0 + e1) + (e2 + e3);

    // sZ = dot(fb_i, g), dd = dot(fb_i, fc_i) from the f32 feat row
    const float* fr = feat + (size_t)i * K_DIM;
    float sZ = 0.f, dd = 0.f;
    #pragma unroll 8
    for (int k4 = 0; k4 < 32; ++k4) {
        float4 v = ((const float4*)fr)[k4];
        const float fb0 = bf2f(f2bf(v.x)), fc0 = bf2f(f2bf(v.x * C_SCALE));
        const float fb1 = bf2f(f2bf(v.y)), fc1 = bf2f(f2bf(v.y * C_SCALE));
        const float fb2 = bf2f(f2bf(v.z)), fc2 = bf2f(f2bf(v.z * C_SCALE));
        const float fb3 = bf2f(f2bf(v.w)), fc3 = bf2f(f2bf(v.w * C_SCALE));
        const float* gv = &g[k4 * 4];
        sZ += fb0 * gv[0]; dd += fb0 * fc0;
        sZ += fb1 * gv[1]; dd += fb1 * fc1;
        sZ += fb2 * gv[2]; dd += fb2 * fc2;
        sZ += fb3 * gv[3]; dd += fb3 * fc3;
    }

    const int Nn = shNn;
    float contrib;
    if (nf[i]) {
        const float cnt = (float)(Nn - 1);
        const float denom = ep + Psum[i];        // + RAW proto logit sum (faithful)
        const float sp = sZ - dd;                // sum_{j novel, j!=i} D_ij
        const float num = sp * LN2 - logf(denom) * cnt;
        const float sc = cnt > 0.f ? cnt : 1.f;
        contrib = -(num / sc);
    } else {
        contrib = -(PLab[i] - logf(ep + expPsum[i]));
    }
    for (int off = 1; off < 64; off <<= 1) contrib += __shfl_xor(contrib, off);
    if ((tid & 63) == 0) red[tid >> 6] = contrib;
    __syncthreads();
    if (tid == 0) atomicAdd(out, (red[0] + red[1]) * (1.0f / (float)M_TOT));
}

// ---------------------------------------------------------------- launch
extern "C" void kernel_launch(void* const* d_in, const int* in_sizes, int n_in,
                              void* d_out, int out_size, void* d_ws, size_t ws_size,
                              hipStream_t stream) {
    const float* feat    = (const float*)d_in[0];
    const int*   labels  = (const int*)d_in[1];
    const float* protos  = (const float*)d_in[2];
    const int*   plabels = (const int*)d_in[3];
    float* out = (float*)d_out;

    char* ws = (char*)d_ws;
    float* rowE    = (float*)ws;                     // 32 x 8192 fp32 (1 MB)
    int*   nfpart  = (int*)(ws + 1048576);           // 32 ints
    int*   nf      = (int*)(ws + 1052672);           // 8192 ints
    float* Psum    = (float*)(ws + 1085440);
    float* expPsum = (float*)(ws + 1118208);
    float* PLab    = (float*)(ws + 1150976);
    float* gpart   = (float*)(ws + 1183744);         // 32 x 128 fp32

    k_sym<<<NBLK, 512, 0, stream>>>(feat, labels, protos, plabels,
                                    rowE, nfpart, nf,
                                    Psum, expPsum, PLab, gpart, out);
    k_final<<<64, 128, 0, stream>>>(feat, rowE, Psum, expPsum, PLab,
                                    nf, nfpart, gpart, out);
}